// Round 3
// baseline (323.512 us; speedup 1.0000x reference)
//
#include <hip/hip_runtime.h>
#include <cstdint>
#include <cstddef>

typedef unsigned short u16;
typedef __attribute__((ext_vector_type(4))) float f32x4;
typedef __attribute__((ext_vector_type(8))) short bf16x8;

__device__ __forceinline__ u16 f2bf(float f) {
  unsigned int u = __builtin_bit_cast(unsigned int, f);
  u += 0x7fffu + ((u >> 16) & 1u);
  return (u16)(u >> 16);
}

// async global->LDS DMA, 16B per lane. LDS dest = uniform base + lane*16.
__device__ __forceinline__ void gl_lds16(const u16* g, u16* lds_base) {
  __builtin_amdgcn_global_load_lds(
      (const __attribute__((address_space(1))) unsigned int*)g,
      (__attribute__((address_space(3))) unsigned int*)lds_base, 16, 0, 0);
}

// ---------------- all-weight transpose + fp32->bf16 (one dispatch) ----------------
__global__ __launch_bounds__(256) void transpose_all(const float* __restrict__ s0,
                                                     const float* __restrict__ s1,
                                                     const float* __restrict__ s2,
                                                     const float* __restrict__ s3,
                                                     u16* __restrict__ d0,
                                                     u16* __restrict__ d1,
                                                     u16* __restrict__ d2,
                                                     u16* __restrict__ d3) {
  __shared__ float tile[32][33];
  int idx = blockIdx.x;
  const float* src; u16* dst; int K, N, t;
  if (idx < 1728)      { src = s0; dst = d0; K = 768;  N = 2304; t = idx; }
  else if (idx < 2304) { src = s1; dst = d1; K = 768;  N = 768;  t = idx - 1728; }
  else if (idx < 4608) { src = s2; dst = d2; K = 768;  N = 3072; t = idx - 2304; }
  else                 { src = s3; dst = d3; K = 3072; N = 768;  t = idx - 4608; }
  int nt_n = N >> 5;
  int n0 = (t % nt_n) * 32, k0 = (t / nt_n) * 32;
  int tx = threadIdx.x & 31, ty = threadIdx.x >> 5;  // 32 x 8
#pragma unroll
  for (int i = 0; i < 4; ++i)
    tile[ty + i * 8][tx] = src[(size_t)(k0 + ty + i * 8) * N + n0 + tx];
  __syncthreads();
#pragma unroll
  for (int i = 0; i < 4; ++i)
    dst[(size_t)(n0 + ty + i * 8) * K + k0 + tx] = f2bf(tile[tx][ty + i * 8]);
}

// ---------------- V transpose: qkvb [B*T][2304] -> vt [24][64][2048]; also zeroes ctr ----
__global__ __launch_bounds__(256) void transpose_v(const u16* __restrict__ qkvb,
                                                   u16* __restrict__ vt,
                                                   unsigned int* __restrict__ ctr) {
  __shared__ u16 tile[64 * 72];
  if (blockIdx.x == 0 && blockIdx.y == 0 && threadIdx.x == 0) *ctr = 0u;
  int t0 = blockIdx.x * 64;
  int bh = blockIdx.y;
  int b = bh / 12, h = bh % 12;
  int tid = threadIdx.x;
  int c8 = tid & 7, r = tid >> 3;
#pragma unroll
  for (int i = 0; i < 2; ++i) {
    int rr = r + i * 32;
    *(uint4*)&tile[rr * 72 + c8 * 8] =
        *(const uint4*)&qkvb[(size_t)(b * 2048 + t0 + rr) * 2304 + 1536 + h * 64 + c8 * 8];
  }
  __syncthreads();
#pragma unroll
  for (int i = 0; i < 2; ++i) {
    int dr = r + i * 32;
    u16 tmp[8];
#pragma unroll
    for (int j = 0; j < 8; ++j) tmp[j] = tile[(c8 * 8 + j) * 72 + dr];
    *(uint4*)&vt[((size_t)bh * 64 + dr) * 2048 + t0 + c8 * 8] = *(uint4*)tmp;
  }
}

// ---------------- LayerNorm (row = 768 fp32) -> bf16, float4 loads ----------------
// Optional cpy: raw input row copied to fp32 buffer (seeds residual for split-K atomics).
__global__ __launch_bounds__(192) void ln_rows(const float* __restrict__ x,
                                               const float* __restrict__ g,
                                               const float* __restrict__ bb,
                                               u16* __restrict__ out,
                                               float* __restrict__ cpy) {
  int row = blockIdx.x;
  int t = threadIdx.x;  // 0..191, one float4 each
  float4 v = *(const float4*)(x + (size_t)row * 768 + t * 4);
  if (cpy) *(float4*)(cpy + (size_t)row * 768 + t * 4) = v;
  float s = v.x + v.y + v.z + v.w;
  float sq = v.x * v.x + v.y * v.y + v.z * v.z + v.w * v.w;
#pragma unroll
  for (int o = 32; o > 0; o >>= 1) {
    s += __shfl_down(s, o);
    sq += __shfl_down(sq, o);
  }
  __shared__ float ss[3], s2[3];
  int w = t >> 6;
  if ((t & 63) == 0) { ss[w] = s; s2[w] = sq; }
  __syncthreads();
  s = ss[0] + ss[1] + ss[2];
  sq = s2[0] + s2[1] + s2[2];
  float mu = s * (1.f / 768.f);
  float var = sq * (1.f / 768.f) - mu * mu;
  float rs = rsqrtf(var + 1e-5f);
  float4 gv = *(const float4*)(g + t * 4);
  float4 bv = *(const float4*)(bb + t * 4);
  u16 o4[4];
  o4[0] = f2bf((v.x - mu) * rs * gv.x + bv.x);
  o4[1] = f2bf((v.y - mu) * rs * gv.y + bv.y);
  o4[2] = f2bf((v.z - mu) * rs * gv.z + bv.z);
  o4[3] = f2bf((v.w - mu) * rs * gv.w + bv.w);
  *(uint2*)(out + (size_t)row * 768 + t * 4) = *(uint2*)o4;
}

// ---------------- bf16 MFMA GEMM: C = A[M,K] @ BT[N,K]^T ----------------
// m97-style geometry: block tile 128x128, BK=64, 4 waves in 2x2 quadrants,
// each wave owns a 64x64 sub-tile (acc[4][4]) -> 2.0 MFMA per ds_read_b128.
// Single-barrier double-buffered DMA pipeline.
// EPI: 0 = store bf16; 2 = exact GELU -> bf16
template <int EPI>
__global__ __launch_bounds__(256, 2) void gemm_bt(const u16* __restrict__ A,
                                                  const u16* __restrict__ BT,
                                                  int M, int N, int K,
                                                  u16* __restrict__ outB) {
  __shared__ __align__(16) u16 Al[2][128 * 64];
  __shared__ __align__(16) u16 Bl[2][128 * 64];
  int tid = threadIdx.x;
  int lane = tid & 63, w = tid >> 6;
  int l16 = lane & 15, quad = lane >> 4;
  int swz = l16 & 7;
  int wr = w >> 1, wc = w & 1;  // wave quadrant within 128x128 tile
  size_t rowA0 = (size_t)blockIdx.y * 128;
  size_t rowB0 = (size_t)blockIdx.x * 128;

  auto stage = [&](int buf, int k0) {
#pragma unroll
    for (int i = 0; i < 4; ++i) {
      int cbase = (i * 4 + w) * 64;
      int chunk = cbase + lane;
      int r = chunk >> 3, c8 = (chunk & 7) ^ (r & 7);
      gl_lds16(&A[(rowA0 + r) * (size_t)K + k0 + c8 * 8], &Al[buf][cbase * 8]);
    }
#pragma unroll
    for (int i = 0; i < 4; ++i) {
      int cbase = (i * 4 + w) * 64;
      int chunk = cbase + lane;
      int r = chunk >> 3, c8 = (chunk & 7) ^ (r & 7);
      gl_lds16(&BT[(rowB0 + r) * (size_t)K + k0 + c8 * 8], &Bl[buf][cbase * 8]);
    }
  };

  f32x4 acc[4][4] = {};
  stage(0, 0);
  int cur = 0;
  for (int k0 = 0; k0 < K; k0 += 64) {
    __syncthreads();  // drains DMA for buf[cur]; rendezvous frees buf[cur^1]
    if (k0 + 64 < K) stage(cur ^ 1, k0 + 64);
#pragma unroll
    for (int ks = 0; ks < 2; ++ks) {
      int c = ks * 4 + quad;
      bf16x8 af[4], bf[4];
#pragma unroll
      for (int mt = 0; mt < 4; ++mt)
        af[mt] = *(const bf16x8*)&Al[cur][(wr * 64 + mt * 16 + l16) * 64 + (c ^ swz) * 8];
#pragma unroll
      for (int nt = 0; nt < 4; ++nt)
        bf[nt] = *(const bf16x8*)&Bl[cur][(wc * 64 + nt * 16 + l16) * 64 + (c ^ swz) * 8];
#pragma unroll
      for (int mt = 0; mt < 4; ++mt)
#pragma unroll
        for (int nt = 0; nt < 4; ++nt)
          acc[mt][nt] = __builtin_amdgcn_mfma_f32_16x16x32_bf16(af[mt], bf[nt], acc[mt][nt], 0, 0, 0);
    }
    cur ^= 1;
  }

#pragma unroll
  for (int mt = 0; mt < 4; ++mt) {
#pragma unroll
    for (int i = 0; i < 4; ++i) {
      size_t row = rowA0 + wr * 64 + mt * 16 + quad * 4 + i;
#pragma unroll
      for (int nt = 0; nt < 4; ++nt) {
        size_t col = rowB0 + wc * 64 + nt * 16 + l16;
        float v = acc[mt][nt][i];
        if (EPI == 0) {
          outB[row * N + col] = f2bf(v);
        } else {
          float ge = 0.5f * v * (1.f + erff(v * 0.70710678118654752f));
          outB[row * N + col] = f2bf(ge);
        }
      }
    }
  }
}

// ---------------- split-K GEMM for N=768 projections ----------------
// Same 128x128 pipeline; blockIdx.z picks K-chunk of size KC; epilogue
// accumulates into fp32 buffer (pre-seeded with the residual) via
// fire-and-forget HW fp32 atomics. Restores grid parallelism for small N.
template <int KC>
__global__ __launch_bounds__(256, 2) void gemm_bt_sk(const u16* __restrict__ A,
                                                     const u16* __restrict__ BT,
                                                     int N, int K,
                                                     float* __restrict__ outF) {
  __shared__ __align__(16) u16 Al[2][128 * 64];
  __shared__ __align__(16) u16 Bl[2][128 * 64];
  int tid = threadIdx.x;
  int lane = tid & 63, w = tid >> 6;
  int l16 = lane & 15, quad = lane >> 4;
  int swz = l16 & 7;
  int wr = w >> 1, wc = w & 1;
  size_t rowA0 = (size_t)blockIdx.y * 128;
  size_t rowB0 = (size_t)blockIdx.x * 128;
  int koff = blockIdx.z * KC;

  auto stage = [&](int buf, int k0) {
#pragma unroll
    for (int i = 0; i < 4; ++i) {
      int cbase = (i * 4 + w) * 64;
      int chunk = cbase + lane;
      int r = chunk >> 3, c8 = (chunk & 7) ^ (r & 7);
      gl_lds16(&A[(rowA0 + r) * (size_t)K + k0 + c8 * 8], &Al[buf][cbase * 8]);
    }
#pragma unroll
    for (int i = 0; i < 4; ++i) {
      int cbase = (i * 4 + w) * 64;
      int chunk = cbase + lane;
      int r = chunk >> 3, c8 = (chunk & 7) ^ (r & 7);
      gl_lds16(&BT[(rowB0 + r) * (size_t)K + k0 + c8 * 8], &Bl[buf][cbase * 8]);
    }
  };

  f32x4 acc[4][4] = {};
  stage(0, koff);
  int cur = 0;
  for (int k0 = koff; k0 < koff + KC; k0 += 64) {
    __syncthreads();
    if (k0 + 64 < koff + KC) stage(cur ^ 1, k0 + 64);
#pragma unroll
    for (int ks = 0; ks < 2; ++ks) {
      int c = ks * 4 + quad;
      bf16x8 af[4], bf[4];
#pragma unroll
      for (int mt = 0; mt < 4; ++mt)
        af[mt] = *(const bf16x8*)&Al[cur][(wr * 64 + mt * 16 + l16) * 64 + (c ^ swz) * 8];
#pragma unroll
      for (int nt = 0; nt < 4; ++nt)
        bf[nt] = *(const bf16x8*)&Bl[cur][(wc * 64 + nt * 16 + l16) * 64 + (c ^ swz) * 8];
#pragma unroll
      for (int mt = 0; mt < 4; ++mt)
#pragma unroll
        for (int nt = 0; nt < 4; ++nt)
          acc[mt][nt] = __builtin_amdgcn_mfma_f32_16x16x32_bf16(af[mt], bf[nt], acc[mt][nt], 0, 0, 0);
    }
    cur ^= 1;
  }

#pragma unroll
  for (int mt = 0; mt < 4; ++mt) {
#pragma unroll
    for (int i = 0; i < 4; ++i) {
      size_t row = rowA0 + wr * 64 + mt * 16 + quad * 4 + i;
#pragma unroll
      for (int nt = 0; nt < 4; ++nt) {
        size_t col = rowB0 + wc * 64 + nt * 16 + l16;
        unsafeAtomicAdd(&outF[row * N + col], acc[mt][nt][i]);
      }
    }
  }
}

// ---------------- causal flash attention, split-K load-balanced + pipelined staging ----
__global__ __launch_bounds__(256, 3) void flash_attn(const u16* __restrict__ qkv,
                                                     const u16* __restrict__ vt,
                                                     u16* __restrict__ y,
                                                     float* __restrict__ OP,
                                                     float* __restrict__ LP,
                                                     unsigned int* __restrict__ ctr) {
  __shared__ __align__(16) u16 Kl[128 * 64];   // [tok][d], chunk-swizzled
  __shared__ __align__(16) u16 Vl[64 * 128];   // [d][tok], chunk-swizzled
  __shared__ __align__(16) u16 Pl[4][16 * 136];
  __shared__ unsigned int s_unit;

  int tid = threadIdx.x;
  int lane = tid & 63, w = tid >> 6;
  int l16 = lane & 15, quad = lane >> 4;
  int swz = l16 & 7;
  u16* Pw = &Pl[w][0];

  for (;;) {
    __syncthreads();
    if (tid == 0) s_unit = atomicAdd(ctr, 1u);
    __syncthreads();
    unsigned int u = s_unit;
    if (u >= 1152u) return;

    int qt, bh, kb0, kb1, part;
    bool heavy;
    if (u < 384u) {
      int t = (int)u;
      qt = 31 - t / 24; bh = t % 24;
      part = 0; kb0 = 0; kb1 = 8; heavy = true;
    } else if (u < 768u) {
      int t = (int)u - 384;
      qt = 31 - t / 24; bh = t % 24;
      part = 1; kb0 = 8; kb1 = qt / 2 + 1; heavy = true;
    } else {
      int t = (int)u - 768;
      qt = 15 - t / 24; bh = t % 24;
      part = 0; kb0 = 0; kb1 = qt / 2 + 1; heavy = false;
    }
    int b = bh / 12, h = bh % 12;
    int qw = qt * 64 + w * 16;
    int kdiag = qt / 2;  // k-block containing the diagonal (== nkb-1)

    const u16* base = qkv + (size_t)b * 2048 * 2304;
    const u16* vbase = vt + (size_t)bh * 64 * 2048;

    bf16x8 qf0, qf1;
    {
      const u16* qp = base + (size_t)(qw + l16) * 2304 + h * 64 + quad * 8;
      qf0 = *(const bf16x8*)qp;
      qf1 = *(const bf16x8*)(qp + 32);
    }

    f32x4 O[4] = {};
    float l_i[4] = {0.f, 0.f, 0.f, 0.f};  // per-lane partial row sums

    const float sc = 0.125f * 1.44269504088896340736f;

    auto stageK = [&](int kt0) {
#pragma unroll
      for (int i = 0; i < 4; ++i) {
        int cbase = (i * 4 + w) * 64;
        int chunk = cbase + lane;
        int r = chunk >> 3, c8 = (chunk & 7) ^ (r & 7);
        gl_lds16(base + (size_t)(kt0 + r) * 2304 + 768 + h * 64 + c8 * 8, &Kl[cbase * 8]);
      }
    };
    auto stageV = [&](int kt0) {
#pragma unroll
      for (int i = 0; i < 4; ++i) {
        int cbase = (i * 4 + w) * 64;
        int chunk = cbase + lane;
        int r = chunk >> 4, c16 = (chunk & 15) ^ (r & 7);
        gl_lds16(vbase + (size_t)r * 2048 + kt0 + c16 * 8, &Vl[cbase * 8]);
      }
    };

    stageK(kb0 << 7);  // Kl free: all waves passed the unit-decode barriers
    for (int kb = kb0; kb < kb1; ++kb) {
      int kt0 = kb << 7;
      __syncthreads();  // drains K(kb) DMA (in flight during prev PV); Vl free
      stageV(kt0);      // V-DMA flies under QK^T + exp

      f32x4 S[8];
#pragma unroll
      for (int nt = 0; nt < 8; ++nt) {
        bf16x8 k0 = *(const bf16x8*)&Kl[(nt * 16 + l16) * 64 + (quad ^ swz) * 8];
        bf16x8 k1 = *(const bf16x8*)&Kl[(nt * 16 + l16) * 64 + ((4 + quad) ^ swz) * 8];
        f32x4 z = {};
        z = __builtin_amdgcn_mfma_f32_16x16x32_bf16(qf0, k0, z, 0, 0, 0);
        S[nt] = __builtin_amdgcn_mfma_f32_16x16x32_bf16(qf1, k1, z, 0, 0, 0);
      }

      bool diag = (kb == kdiag);
#pragma unroll
      for (int nt = 0; nt < 8; ++nt) {
        int tk = kt0 + nt * 16 + l16;
#pragma unroll
        for (int i = 0; i < 4; ++i) {
          float p = exp2f(S[nt][i] * sc);
          if (diag && tk > qw + quad * 4 + i) p = 0.f;
          l_i[i] += p;
          Pw[(quad * 4 + i) * 136 + nt * 16 + l16] =
              (u16)(__builtin_bit_cast(unsigned int, p) >> 16);
        }
      }

      __syncthreads();                   // drains V(kb) DMA; Kl free; P visible (lgkmcnt)
      if (kb + 1 < kb1) stageK((kb + 1) << 7);  // next-K DMA flies under PV

#pragma unroll
      for (int c = 0; c < 4; ++c) {
        bf16x8 pf = *(const bf16x8*)&Pw[l16 * 136 + c * 32 + quad * 8];
#pragma unroll
        for (int dt = 0; dt < 4; ++dt) {
          bf16x8 vf = *(const bf16x8*)&Vl[(dt * 16 + l16) * 128 + ((c * 4 + quad) ^ swz) * 8];
          O[dt] = __builtin_amdgcn_mfma_f32_16x16x32_bf16(pf, vf, O[dt], 0, 0, 0);
        }
      }
    }

#pragma unroll
    for (int i = 0; i < 4; ++i) {
#pragma unroll
      for (int o = 1; o < 16; o <<= 1) l_i[i] += __shfl_xor(l_i[i], o);
    }

    if (heavy) {
      size_t tno = (size_t)(bh * 16 + (qt - 16)) * 2 + part;
      float* op = OP + tno * 4096;
      float* lp = LP + tno * 64;
#pragma unroll
      for (int dt = 0; dt < 4; ++dt) {
#pragma unroll
        for (int i = 0; i < 4; ++i)
          op[(w * 16 + quad * 4 + i) * 64 + dt * 16 + l16] = O[dt][i];
      }
      if (l16 == 0) {
#pragma unroll
        for (int i = 0; i < 4; ++i) lp[w * 16 + quad * 4 + i] = l_i[i];
      }
    } else {
#pragma unroll
      for (int dt = 0; dt < 4; ++dt) {
#pragma unroll
        for (int i = 0; i < 4; ++i) {
          int tq = qw + quad * 4 + i;
          float ov = O[dt][i] / l_i[i];
          y[(size_t)(b * 2048 + tq) * 768 + h * 64 + dt * 16 + l16] = f2bf(ov);
        }
      }
    }
  }
}

// ---------------- combine split-K partials for heavy q-tiles (qt 16..31) ----------------
__global__ __launch_bounds__(256) void attn_combine(const float* __restrict__ OP,
                                                    const float* __restrict__ LP,
                                                    u16* __restrict__ y) {
  int t = blockIdx.x;            // 0..383 : bh*16 + (qt-16)
  int bh = t >> 4, qth = t & 15;
  int b = bh / 12, h = bh % 12;
  int tid = threadIdx.x;
  int r = tid >> 2;              // 0..63 row within tile
  int c0 = (tid & 3) << 4;       // 0,16,32,48
  const float* a = OP + (size_t)t * 2 * 4096 + r * 64 + c0;
  const float* bp = a + 4096;
  float inv = 1.f / (LP[(size_t)t * 128 + r] + LP[(size_t)t * 128 + 64 + r]);
  u16 ob[16];
#pragma unroll
  for (int j = 0; j < 16; ++j) ob[j] = f2bf((a[j] + bp[j]) * inv);
  size_t row = (size_t)b * 2048 + (size_t)(16 + qth) * 64 + r;
  u16* yp = y + row * 768 + h * 64 + c0;
  *(uint4*)yp = *(uint4*)&ob[0];
  *(uint4*)(yp + 8) = *(uint4*)&ob[8];
}

// ---------------- launch ----------------
extern "C" void kernel_launch(void* const* d_in, const int* in_sizes, int n_in,
                              void* d_out, int out_size, void* d_ws, size_t ws_size,
                              hipStream_t stream) {
  const float* x      = (const float*)d_in[0];
  const float* ln1_g  = (const float*)d_in[1];
  const float* ln1_b  = (const float*)d_in[2];
  const float* W_qkv  = (const float*)d_in[3];
  const float* W_attn = (const float*)d_in[4];
  const float* ln2_g  = (const float*)d_in[5];
  const float* ln2_b  = (const float*)d_in[6];
  const float* W_fc   = (const float*)d_in[7];
  const float* W_mlp  = (const float*)d_in[8];
  float* out = (float*)d_out;

  const int M = 4096;  // B*T
  char* p = (char*)d_ws;
  auto alloc = [&](size_t bytes) {
    char* r = p;
    p += (bytes + 255) & ~(size_t)255;
    return r;
  };
  u16* wt_qkv  = (u16*)alloc((size_t)2304 * 768 * 2);
  u16* wt_attn = (u16*)alloc((size_t)768 * 768 * 2);
  u16* wt_fc   = (u16*)alloc((size_t)3072 * 768 * 2);
  u16* wt_mlp  = (u16*)alloc((size_t)768 * 3072 * 2);
  u16* xn1     = (u16*)alloc((size_t)M * 768 * 2);
  u16* qkvb    = (u16*)alloc((size_t)M * 2304 * 2);
  u16* yb      = (u16*)alloc((size_t)M * 768 * 2);
  float* x1    = (float*)alloc((size_t)M * 768 * 4);
  u16* xn2     = (u16*)alloc((size_t)M * 768 * 2);
  u16* hb      = (u16*)alloc((size_t)M * 3072 * 2);
  u16* vt      = (u16*)alloc((size_t)24 * 64 * 2048 * 2);
  unsigned int* ctr = (unsigned int*)alloc(256);

  // split-K attention partials alias the (not yet live) hb region:
  // OP = 24*16*2*4096 fp32 (12.6 MB), LP = 24*16*2*64 fp32; hb is 25.2 MB.
  float* OPb = (float*)hb;
  float* LPb = OPb + (size_t)24 * 16 * 2 * 4096;

  // all 4 weight transposes in one dispatch (6912 tiles)
  transpose_all<<<6912, 256, 0, stream>>>(W_qkv, W_attn, W_fc, W_mlp,
                                          wt_qkv, wt_attn, wt_fc, wt_mlp);

  // ln1: xn1 = LN(x); also seed x1 = x (residual base for attn-proj atomics)
  ln_rows<<<M, 192, 0, stream>>>(x, ln1_g, ln1_b, xn1, x1);
  // QKV = xn1 @ W_qkv -> bf16   (128x128 tiles: 18 x 32)
  gemm_bt<0><<<dim3(2304 / 128, M / 128), 256, 0, stream>>>(xn1, wt_qkv, M, 2304, 768,
                                                            qkvb);
  transpose_v<<<dim3(32, 24), 256, 0, stream>>>(qkvb, vt, ctr);
  flash_attn<<<768, 256, 0, stream>>>(qkvb, vt, yb, OPb, LPb, ctr);
  attn_combine<<<384, 256, 0, stream>>>(OPb, LPb, yb);
  // x1 += yb @ W_attn_proj (split-K2: 6 x 32 x 2 = 384 blocks, HW fp32 atomics)
  gemm_bt_sk<384><<<dim3(768 / 128, M / 128, 2), 256, 0, stream>>>(yb, wt_attn, 768, 768, x1);
  // ln2: xn2 = LN(x1); also seed out = x1 (residual base for mlp-proj atomics)
  ln_rows<<<M, 192, 0, stream>>>(x1, ln2_g, ln2_b, xn2, out);
  // h = gelu(xn2 @ W_fc) -> bf16  (24 x 32)
  gemm_bt<2><<<dim3(3072 / 128, M / 128), 256, 0, stream>>>(xn2, wt_fc, M, 3072, 768,
                                                            hb);
  // out += hb @ W_mlp_proj (split-K4: 6 x 32 x 4 = 768 blocks, HW fp32 atomics)
  gemm_bt_sk<768><<<dim3(768 / 128, M / 128, 4), 256, 0, stream>>>(hb, wt_mlp, 768, 3072, out);
}

// Round 4
// 261.976 us; speedup vs baseline: 1.2349x; 1.2349x over previous
//
#include <hip/hip_runtime.h>
#include <cstdint>
#include <cstddef>

typedef unsigned short u16;
typedef __attribute__((ext_vector_type(4))) float f32x4;
typedef __attribute__((ext_vector_type(8))) short bf16x8;

__device__ __forceinline__ u16 f2bf(float f) {
  unsigned int u = __builtin_bit_cast(unsigned int, f);
  u += 0x7fffu + ((u >> 16) & 1u);
  return (u16)(u >> 16);
}

// async global->LDS DMA, 16B per lane. LDS dest = uniform base + lane*16.
__device__ __forceinline__ void gl_lds16(const u16* g, u16* lds_base) {
  __builtin_amdgcn_global_load_lds(
      (const __attribute__((address_space(1))) unsigned int*)g,
      (__attribute__((address_space(3))) unsigned int*)lds_base, 16, 0, 0);
}

// ---------------- all-weight transpose + fp32->bf16 (one dispatch) ----------------
__global__ __launch_bounds__(256) void transpose_all(const float* __restrict__ s0,
                                                     const float* __restrict__ s1,
                                                     const float* __restrict__ s2,
                                                     const float* __restrict__ s3,
                                                     u16* __restrict__ d0,
                                                     u16* __restrict__ d1,
                                                     u16* __restrict__ d2,
                                                     u16* __restrict__ d3) {
  __shared__ float tile[32][33];
  int idx = blockIdx.x;
  const float* src; u16* dst; int K, N, t;
  if (idx < 1728)      { src = s0; dst = d0; K = 768;  N = 2304; t = idx; }
  else if (idx < 2304) { src = s1; dst = d1; K = 768;  N = 768;  t = idx - 1728; }
  else if (idx < 4608) { src = s2; dst = d2; K = 768;  N = 3072; t = idx - 2304; }
  else                 { src = s3; dst = d3; K = 3072; N = 768;  t = idx - 4608; }
  int nt_n = N >> 5;
  int n0 = (t % nt_n) * 32, k0 = (t / nt_n) * 32;
  int tx = threadIdx.x & 31, ty = threadIdx.x >> 5;  // 32 x 8
#pragma unroll
  for (int i = 0; i < 4; ++i)
    tile[ty + i * 8][tx] = src[(size_t)(k0 + ty + i * 8) * N + n0 + tx];
  __syncthreads();
#pragma unroll
  for (int i = 0; i < 4; ++i)
    dst[(size_t)(n0 + ty + i * 8) * K + k0 + tx] = f2bf(tile[tx][ty + i * 8]);
}

// ---------------- V transpose: qkvb [B*T][2304] -> vt [24][64][2048]; also zeroes ctr ----
__global__ __launch_bounds__(256) void transpose_v(const u16* __restrict__ qkvb,
                                                   u16* __restrict__ vt,
                                                   unsigned int* __restrict__ ctr) {
  __shared__ u16 tile[64 * 72];
  if (blockIdx.x == 0 && blockIdx.y == 0 && threadIdx.x == 0) *ctr = 0u;
  int t0 = blockIdx.x * 64;
  int bh = blockIdx.y;
  int b = bh / 12, h = bh % 12;
  int tid = threadIdx.x;
  int c8 = tid & 7, r = tid >> 3;
#pragma unroll
  for (int i = 0; i < 2; ++i) {
    int rr = r + i * 32;
    *(uint4*)&tile[rr * 72 + c8 * 8] =
        *(const uint4*)&qkvb[(size_t)(b * 2048 + t0 + rr) * 2304 + 1536 + h * 64 + c8 * 8];
  }
  __syncthreads();
#pragma unroll
  for (int i = 0; i < 2; ++i) {
    int dr = r + i * 32;
    u16 tmp[8];
#pragma unroll
    for (int j = 0; j < 8; ++j) tmp[j] = tile[(c8 * 8 + j) * 72 + dr];
    *(uint4*)&vt[((size_t)bh * 64 + dr) * 2048 + t0 + c8 * 8] = *(uint4*)tmp;
  }
}

// ---------------- LayerNorm (row = 768 fp32) -> bf16, float4 loads ----------------
__global__ __launch_bounds__(192) void ln_rows(const float* __restrict__ x,
                                               const float* __restrict__ g,
                                               const float* __restrict__ bb,
                                               u16* __restrict__ out) {
  int row = blockIdx.x;
  int t = threadIdx.x;  // 0..191, one float4 each
  float4 v = *(const float4*)(x + (size_t)row * 768 + t * 4);
  float s = v.x + v.y + v.z + v.w;
  float sq = v.x * v.x + v.y * v.y + v.z * v.z + v.w * v.w;
#pragma unroll
  for (int o = 32; o > 0; o >>= 1) {
    s += __shfl_down(s, o);
    sq += __shfl_down(sq, o);
  }
  __shared__ float ss[3], s2[3];
  int w = t >> 6;
  if ((t & 63) == 0) { ss[w] = s; s2[w] = sq; }
  __syncthreads();
  s = ss[0] + ss[1] + ss[2];
  sq = s2[0] + s2[1] + s2[2];
  float mu = s * (1.f / 768.f);
  float var = sq * (1.f / 768.f) - mu * mu;
  float rs = rsqrtf(var + 1e-5f);
  float4 gv = *(const float4*)(g + t * 4);
  float4 bv = *(const float4*)(bb + t * 4);
  u16 o4[4];
  o4[0] = f2bf((v.x - mu) * rs * gv.x + bv.x);
  o4[1] = f2bf((v.y - mu) * rs * gv.y + bv.y);
  o4[2] = f2bf((v.z - mu) * rs * gv.z + bv.z);
  o4[3] = f2bf((v.w - mu) * rs * gv.w + bv.w);
  *(uint2*)(out + (size_t)row * 768 + t * 4) = *(uint2*)o4;
}

// ---------------- bf16 MFMA GEMM: C = A[M,K] @ BT[N,K]^T ----------------
// Round-1 proven geometry. Double-buffered single-barrier pipeline: per iter ->
// barrier; issue DMA(next tile); compute current tile.
// Block tile TM x 64, 4 waves stacked on M. TM=128 (MT=2) or TM=64 (MT=1).
// NEW: XCD-aware bijective block swizzle (nwg % 8 == 0 for all our grids):
// hw block i lands on XCD i%8; remap so each XCD sweeps a CONTIGUOUS x-major
// tile range -> A row-panels + B panels stay hot in that XCD's private L2.
// EPI: 0 = store bf16; 1 = residual(fp32) add, store fp32; 2 = exact GELU -> bf16
template <int EPI, int TM>
__global__ __launch_bounds__(256, 3) void gemm_bt(const u16* __restrict__ A,
                                                  const u16* __restrict__ BT,
                                                  int M, int N, int K,
                                                  float* __restrict__ outF,
                                                  u16* __restrict__ outB,
                                                  const float* __restrict__ res) {
  constexpr int MT = TM / 64;  // 16-row m-frags per wave (TM/4 rows per wave)
  __shared__ __align__(16) u16 Al[2][TM * 64];
  __shared__ __align__(16) u16 Bl[2][64 * 64];
  int tid = threadIdx.x;
  int lane = tid & 63, w = tid >> 6;
  int l16 = lane & 15, quad = lane >> 4;
  int swz = l16 & 7;

  // XCD swizzle (bijective since gridDim.x*gridDim.y % 8 == 0)
  int gx = gridDim.x;
  int nwg = gx * gridDim.y;
  int wg = blockIdx.y * gx + blockIdx.x;
  int chunk = nwg >> 3;
  int swg = (wg & 7) * chunk + (wg >> 3);
  int bx = swg % gx, by = swg / gx;

  size_t rowA0 = (size_t)by * TM;
  size_t rowB0 = (size_t)bx * 64;

  auto stage = [&](int buf, int k0) {
#pragma unroll
    for (int i = 0; i < TM / 32; ++i) {
      int cbase = (i * 4 + w) * 64;
      int chunk2 = cbase + lane;
      int r = chunk2 >> 3, c8 = (chunk2 & 7) ^ (r & 7);  // swizzled source chunk
      gl_lds16(&A[(rowA0 + r) * (size_t)K + k0 + c8 * 8], &Al[buf][cbase * 8]);
    }
#pragma unroll
    for (int i = 0; i < 2; ++i) {
      int cbase = (i * 4 + w) * 64;
      int chunk2 = cbase + lane;
      int r = chunk2 >> 3, c8 = (chunk2 & 7) ^ (r & 7);
      gl_lds16(&BT[(rowB0 + r) * (size_t)K + k0 + c8 * 8], &Bl[buf][cbase * 8]);
    }
  };

  f32x4 acc[MT][4] = {};
  stage(0, 0);
  int cur = 0;
  for (int k0 = 0; k0 < K; k0 += 64) {
    __syncthreads();  // drains DMA for buf[cur] (in flight during prev compute);
                      // rendezvous frees buf[cur^1] for overwrite
    if (k0 + 64 < K) stage(cur ^ 1, k0 + 64);
#pragma unroll
    for (int ks = 0; ks < 2; ++ks) {
      int c = ks * 4 + quad;
      bf16x8 af[MT], bf[4];
#pragma unroll
      for (int mt = 0; mt < MT; ++mt)
        af[mt] = *(const bf16x8*)&Al[cur][(w * (TM / 4) + mt * 16 + l16) * 64 + (c ^ swz) * 8];
#pragma unroll
      for (int nt = 0; nt < 4; ++nt)
        bf[nt] = *(const bf16x8*)&Bl[cur][(nt * 16 + l16) * 64 + (c ^ swz) * 8];
#pragma unroll
      for (int mt = 0; mt < MT; ++mt)
#pragma unroll
        for (int nt = 0; nt < 4; ++nt)
          acc[mt][nt] = __builtin_amdgcn_mfma_f32_16x16x32_bf16(af[mt], bf[nt], acc[mt][nt], 0, 0, 0);
    }
    cur ^= 1;
  }

#pragma unroll
  for (int mt = 0; mt < MT; ++mt) {
#pragma unroll
    for (int i = 0; i < 4; ++i) {
      size_t row = rowA0 + w * (TM / 4) + mt * 16 + quad * 4 + i;
#pragma unroll
      for (int nt = 0; nt < 4; ++nt) {
        size_t col = rowB0 + nt * 16 + l16;
        float v = acc[mt][nt][i];
        if (EPI == 0) {
          outB[row * N + col] = f2bf(v);
        } else if (EPI == 1) {
          outF[row * N + col] = res[row * N + col] + v;
        } else {
          float ge = 0.5f * v * (1.f + erff(v * 0.70710678118654752f));
          outB[row * N + col] = f2bf(ge);
        }
      }
    }
  }
}

// ---------------- causal flash attention, split-K load-balanced + pipelined staging ----
// Work units (1152 total, heavy-first):
//   u in [0,384):    heavy tiles qt>=16, part0: kb [0,8)        (size 8)
//   u in [384,768):  heavy tiles qt>=16, part1: kb [8,nkb)      (size 1..8, desc in qt)
//   u in [768,1152): light tiles qt<16:         kb [0,nkb)      (size 1..8, desc in qt)
// No running max => partial (O,l) are additive; heavy parts write fp32 partials,
// attn_combine sums+normalizes. Staging is phase-split: V-DMA flies under QK^T+exp,
// next-K-DMA flies under PV (drains coincide with the existing __syncthreads).
__global__ __launch_bounds__(256, 3) void flash_attn(const u16* __restrict__ qkv,
                                                     const u16* __restrict__ vt,
                                                     u16* __restrict__ y,
                                                     float* __restrict__ OP,
                                                     float* __restrict__ LP,
                                                     unsigned int* __restrict__ ctr) {
  __shared__ __align__(16) u16 Kl[128 * 64];   // [tok][d], chunk-swizzled
  __shared__ __align__(16) u16 Vl[64 * 128];   // [d][tok], chunk-swizzled
  __shared__ __align__(16) u16 Pl[4][16 * 136];
  __shared__ unsigned int s_unit;

  int tid = threadIdx.x;
  int lane = tid & 63, w = tid >> 6;
  int l16 = lane & 15, quad = lane >> 4;
  int swz = l16 & 7;
  u16* Pw = &Pl[w][0];

  for (;;) {
    __syncthreads();
    if (tid == 0) s_unit = atomicAdd(ctr, 1u);
    __syncthreads();
    unsigned int u = s_unit;
    if (u >= 1152u) return;

    int qt, bh, kb0, kb1, part;
    bool heavy;
    if (u < 384u) {
      int t = (int)u;
      qt = 31 - t / 24; bh = t % 24;
      part = 0; kb0 = 0; kb1 = 8; heavy = true;
    } else if (u < 768u) {
      int t = (int)u - 384;
      qt = 31 - t / 24; bh = t % 24;
      part = 1; kb0 = 8; kb1 = qt / 2 + 1; heavy = true;
    } else {
      int t = (int)u - 768;
      qt = 15 - t / 24; bh = t % 24;
      part = 0; kb0 = 0; kb1 = qt / 2 + 1; heavy = false;
    }
    int b = bh / 12, h = bh % 12;
    int qw = qt * 64 + w * 16;
    int kdiag = qt / 2;  // k-block containing the diagonal (== nkb-1)

    const u16* base = qkv + (size_t)b * 2048 * 2304;
    const u16* vbase = vt + (size_t)bh * 64 * 2048;

    bf16x8 qf0, qf1;
    {
      const u16* qp = base + (size_t)(qw + l16) * 2304 + h * 64 + quad * 8;
      qf0 = *(const bf16x8*)qp;
      qf1 = *(const bf16x8*)(qp + 32);
    }

    f32x4 O[4] = {};
    float l_i[4] = {0.f, 0.f, 0.f, 0.f};  // per-lane partial row sums

    const float sc = 0.125f * 1.44269504088896340736f;

    auto stageK = [&](int kt0) {
#pragma unroll
      for (int i = 0; i < 4; ++i) {
        int cbase = (i * 4 + w) * 64;
        int chunk = cbase + lane;
        int r = chunk >> 3, c8 = (chunk & 7) ^ (r & 7);
        gl_lds16(base + (size_t)(kt0 + r) * 2304 + 768 + h * 64 + c8 * 8, &Kl[cbase * 8]);
      }
    };
    auto stageV = [&](int kt0) {
#pragma unroll
      for (int i = 0; i < 4; ++i) {
        int cbase = (i * 4 + w) * 64;
        int chunk = cbase + lane;
        int r = chunk >> 4, c16 = (chunk & 15) ^ (r & 7);
        gl_lds16(vbase + (size_t)r * 2048 + kt0 + c16 * 8, &Vl[cbase * 8]);
      }
    };

    stageK(kb0 << 7);  // Kl free: all waves passed the unit-decode barriers
    for (int kb = kb0; kb < kb1; ++kb) {
      int kt0 = kb << 7;
      __syncthreads();  // drains K(kb) DMA (in flight during prev PV); Vl free
      stageV(kt0);      // V-DMA flies under QK^T + exp

      f32x4 S[8];
#pragma unroll
      for (int nt = 0; nt < 8; ++nt) {
        bf16x8 k0 = *(const bf16x8*)&Kl[(nt * 16 + l16) * 64 + (quad ^ swz) * 8];
        bf16x8 k1 = *(const bf16x8*)&Kl[(nt * 16 + l16) * 64 + ((4 + quad) ^ swz) * 8];
        f32x4 z = {};
        z = __builtin_amdgcn_mfma_f32_16x16x32_bf16(qf0, k0, z, 0, 0, 0);
        S[nt] = __builtin_amdgcn_mfma_f32_16x16x32_bf16(qf1, k1, z, 0, 0, 0);
      }

      bool diag = (kb == kdiag);
#pragma unroll
      for (int nt = 0; nt < 8; ++nt) {
        int tk = kt0 + nt * 16 + l16;
#pragma unroll
        for (int i = 0; i < 4; ++i) {
          float p = exp2f(S[nt][i] * sc);
          if (diag && tk > qw + quad * 4 + i) p = 0.f;
          l_i[i] += p;
          Pw[(quad * 4 + i) * 136 + nt * 16 + l16] =
              (u16)(__builtin_bit_cast(unsigned int, p) >> 16);
        }
      }

      __syncthreads();                   // drains V(kb) DMA; Kl free; P visible (lgkmcnt)
      if (kb + 1 < kb1) stageK((kb + 1) << 7);  // next-K DMA flies under PV

#pragma unroll
      for (int c = 0; c < 4; ++c) {
        bf16x8 pf = *(const bf16x8*)&Pw[l16 * 136 + c * 32 + quad * 8];
#pragma unroll
        for (int dt = 0; dt < 4; ++dt) {
          bf16x8 vf = *(const bf16x8*)&Vl[(dt * 16 + l16) * 128 + ((c * 4 + quad) ^ swz) * 8];
          O[dt] = __builtin_amdgcn_mfma_f32_16x16x32_bf16(pf, vf, O[dt], 0, 0, 0);
        }
      }
    }

#pragma unroll
    for (int i = 0; i < 4; ++i) {
#pragma unroll
      for (int o = 1; o < 16; o <<= 1) l_i[i] += __shfl_xor(l_i[i], o);
    }

    if (heavy) {
      size_t tno = (size_t)(bh * 16 + (qt - 16)) * 2 + part;
      float* op = OP + tno * 4096;
      float* lp = LP + tno * 64;
#pragma unroll
      for (int dt = 0; dt < 4; ++dt) {
#pragma unroll
        for (int i = 0; i < 4; ++i)
          op[(w * 16 + quad * 4 + i) * 64 + dt * 16 + l16] = O[dt][i];
      }
      if (l16 == 0) {
#pragma unroll
        for (int i = 0; i < 4; ++i) lp[w * 16 + quad * 4 + i] = l_i[i];
      }
    } else {
#pragma unroll
      for (int dt = 0; dt < 4; ++dt) {
#pragma unroll
        for (int i = 0; i < 4; ++i) {
          int tq = qw + quad * 4 + i;
          float ov = O[dt][i] / l_i[i];
          y[(size_t)(b * 2048 + tq) * 768 + h * 64 + dt * 16 + l16] = f2bf(ov);
        }
      }
    }
  }
}

// ---------------- combine split-K partials for heavy q-tiles (qt 16..31) ----------------
__global__ __launch_bounds__(256) void attn_combine(const float* __restrict__ OP,
                                                    const float* __restrict__ LP,
                                                    u16* __restrict__ y) {
  int t = blockIdx.x;            // 0..383 : bh*16 + (qt-16)
  int bh = t >> 4, qth = t & 15;
  int b = bh / 12, h = bh % 12;
  int tid = threadIdx.x;
  int r = tid >> 2;              // 0..63 row within tile
  int c0 = (tid & 3) << 4;       // 0,16,32,48
  const float* a = OP + (size_t)t * 2 * 4096 + r * 64 + c0;
  const float* bp = a + 4096;
  float inv = 1.f / (LP[(size_t)t * 128 + r] + LP[(size_t)t * 128 + 64 + r]);
  u16 ob[16];
#pragma unroll
  for (int j = 0; j < 16; ++j) ob[j] = f2bf((a[j] + bp[j]) * inv);
  size_t row = (size_t)b * 2048 + (size_t)(16 + qth) * 64 + r;
  u16* yp = y + row * 768 + h * 64 + c0;
  *(uint4*)yp = *(uint4*)&ob[0];
  *(uint4*)(yp + 8) = *(uint4*)&ob[8];
}

// ---------------- launch ----------------
extern "C" void kernel_launch(void* const* d_in, const int* in_sizes, int n_in,
                              void* d_out, int out_size, void* d_ws, size_t ws_size,
                              hipStream_t stream) {
  const float* x      = (const float*)d_in[0];
  const float* ln1_g  = (const float*)d_in[1];
  const float* ln1_b  = (const float*)d_in[2];
  const float* W_qkv  = (const float*)d_in[3];
  const float* W_attn = (const float*)d_in[4];
  const float* ln2_g  = (const float*)d_in[5];
  const float* ln2_b  = (const float*)d_in[6];
  const float* W_fc   = (const float*)d_in[7];
  const float* W_mlp  = (const float*)d_in[8];
  float* out = (float*)d_out;

  const int M = 4096;  // B*T
  char* p = (char*)d_ws;
  auto alloc = [&](size_t bytes) {
    char* r = p;
    p += (bytes + 255) & ~(size_t)255;
    return r;
  };
  u16* wt_qkv  = (u16*)alloc((size_t)2304 * 768 * 2);
  u16* wt_attn = (u16*)alloc((size_t)768 * 768 * 2);
  u16* wt_fc   = (u16*)alloc((size_t)3072 * 768 * 2);
  u16* wt_mlp  = (u16*)alloc((size_t)768 * 3072 * 2);
  u16* xn1     = (u16*)alloc((size_t)M * 768 * 2);
  u16* qkvb    = (u16*)alloc((size_t)M * 2304 * 2);
  u16* yb      = (u16*)alloc((size_t)M * 768 * 2);
  float* x1    = (float*)alloc((size_t)M * 768 * 4);
  u16* xn2     = (u16*)alloc((size_t)M * 768 * 2);
  u16* hb      = (u16*)alloc((size_t)M * 3072 * 2);
  u16* vt      = (u16*)alloc((size_t)24 * 64 * 2048 * 2);
  unsigned int* ctr = (unsigned int*)alloc(256);

  // split-K attention partials alias the (not yet live) hb region:
  // OP = 24*16*2*4096 fp32 (12.6 MB), LP = 24*16*2*64 fp32; hb is 25.2 MB.
  float* OPb = (float*)hb;
  float* LPb = OPb + (size_t)24 * 16 * 2 * 4096;

  // all 4 weight transposes in one dispatch (6912 tiles)
  transpose_all<<<6912, 256, 0, stream>>>(W_qkv, W_attn, W_fc, W_mlp,
                                          wt_qkv, wt_attn, wt_fc, wt_mlp);

  ln_rows<<<M, 192, 0, stream>>>(x, ln1_g, ln1_b, xn1);
  // QKV = xn1 @ W_qkv -> bf16  (TM=128: 36 x 32 = 1152 blocks)
  gemm_bt<0, 128><<<dim3(2304 / 64, M / 128), 256, 0, stream>>>(xn1, wt_qkv, M, 2304, 768,
                                                                nullptr, qkvb, nullptr);
  transpose_v<<<dim3(32, 24), 256, 0, stream>>>(qkvb, vt, ctr);
  flash_attn<<<768, 256, 0, stream>>>(qkvb, vt, yb, OPb, LPb, ctr);
  attn_combine<<<384, 256, 0, stream>>>(OPb, LPb, yb);
  // x1 = x + y @ W_attn_proj -> fp32  (TM=64: 12 x 64 = 768 blocks)
  gemm_bt<1, 64><<<dim3(768 / 64, M / 64), 256, 0, stream>>>(yb, wt_attn, M, 768, 768,
                                                             x1, nullptr, x);
  ln_rows<<<M, 192, 0, stream>>>(x1, ln2_g, ln2_b, xn2);
  // h = gelu(xn2 @ W_fc) -> bf16  (TM=128: 48 x 32 = 1536 blocks)
  gemm_bt<2, 128><<<dim3(3072 / 64, M / 128), 256, 0, stream>>>(xn2, wt_fc, M, 3072, 768,
                                                                nullptr, hb, nullptr);
  // out = x1 + h @ W_mlp_proj -> fp32  (TM=64: 768 blocks)
  gemm_bt<1, 64><<<dim3(768 / 64, M / 64), 256, 0, stream>>>(hb, wt_mlp, M, 768, 3072,
                                                             out, nullptr, x1);
}